// Round 1
// baseline (186.093 us; speedup 1.0000x reference)
//
#include <hip/hip_runtime.h>

#define WIN      2048
#define HOP      512
#define NFRAMES  16384
#define NBINS    1025   // WIN/2 + 1

// ---------------------------------------------------------------------------
// init: synthesis window rs[j] = (hamming/sqrt(4094)) / env, folded with 1/N.
// env[e] = sum over m == e (mod 512), m in [0,2048) of syn_w[m]^2
// (all shifts k in [-4,4] of _gl_alg are covered by the 4 residue positions)
// ---------------------------------------------------------------------------
__global__ void init_rs_kernel(float* __restrict__ rs) {
    int i = blockIdx.x * blockDim.x + threadIdx.x;
    if (i >= WIN) return;
    const float inv2047 = 1.0f / 2047.0f;
    const float scale   = rsqrtf(4094.0f);       // 1/sqrt(fft_size=(win-1)*2)
    // hamming(n) = 0.54 - 0.46*cos(2*pi*n/2047)
    float sw = (0.54f - 0.46f * cospif(2.0f * (float)i * inv2047)) * scale;
    int   m0 = i & 511;
    float env = 0.0f;
    #pragma unroll
    for (int r = 0; r < 4; ++r) {
        int   m = m0 + 512 * r;
        float h = (0.54f - 0.46f * cospif(2.0f * (float)m * inv2047)) * scale;
        env += h * h;
    }
    rs[i] = sw / env * (1.0f / (float)WIN);      // fold irfft 1/N scaling
}

// ---------------------------------------------------------------------------
// main: one workgroup (256 threads) per frame.
//  1. build Hermitian spectrum in LDS (imag of DC/Nyquist dropped, like irfft)
//  2. 11-stage Stockham radix-2 inverse FFT (autosort, ping-pong LDS buffers)
//  3. fftshift ((j+1024)&2047), window, overlap-add via f32 atomics
// ---------------------------------------------------------------------------
__global__ __launch_bounds__(256) void istft_kernel(
        const float* __restrict__ mag, const float* __restrict__ ph,
        const float* __restrict__ rs, float* __restrict__ out, int out_size) {
    __shared__ float xr[WIN], xi[WIN], yr[WIN], yi[WIN];   // 32 KB ping-pong
    __shared__ float twr[WIN / 2], twi[WIN / 2];           // 8 KB twiddles

    const int tid   = threadIdx.x;
    const int frame = blockIdx.x;
    const float* magf = mag + (size_t)frame * NBINS;
    const float* phf  = ph  + (size_t)frame * NBINS;

    // twiddles for INVERSE transform: exp(+2*pi*i*idx/2048) = cos+i*sin(pi*idx/1024)
    for (int idx = tid; idx < WIN / 2; idx += 256) {
        float s, c;
        sincospif((float)idx * (1.0f / 1024.0f), &s, &c);
        twr[idx] = c; twi[idx] = s;
    }

    // Hermitian-symmetric spectrum fill
    for (int k = tid; k <= 1024; k += 256) {
        float m = magf[k], p = phf[k];
        float s, c;
        sincosf(p, &s, &c);
        float re = m * c, im = m * s;
        if (k == 0 || k == 1024) im = 0.0f;      // irfft ignores DC/Nyquist imag
        xr[k] = re; xi[k] = im;
        if (k > 0 && k < 1024) { xr[WIN - k] = re; xi[WIN - k] = -im; }
    }
    __syncthreads();

    // Stockham radix-2, 11 stages. Reads src[b], src[b+1024];
    // writes dst[b + (b & ~(s-1))] and +s. Twiddle index = b & ~(s-1).
    float *sr = xr, *si = xi, *dr = yr, *di = yi;
    #pragma unroll
    for (int t = 0; t < 11; ++t) {
        const int s = 1 << t;
        #pragma unroll
        for (int bb = 0; bb < 4; ++bb) {
            const int b     = tid + bb * 256;
            const int twidx = b & ~(s - 1);
            const float wr = twr[twidx], wim = twi[twidx];
            const float ar = sr[b],        ai = si[b];
            const float br = sr[b + 1024], bi = si[b + 1024];
            const int o = b + twidx;
            dr[o] = ar + br;
            di[o] = ai + bi;
            const float mr = ar - br, mi = ai - bi;
            dr[o + s] = mr * wr - mi * wim;
            di[o + s] = mr * wim + mi * wr;
        }
        __syncthreads();
        float* t0 = sr; sr = dr; dr = t0;
        float* t1 = si; si = di; di = t1;
    }
    // result (real part) now in sr, natural order

    // fftshift + window + overlap-add (output trimmed by 3*hop = 1536)
    const long base = (long)frame * HOP - 1536;
    for (int j = tid; j < WIN; j += 256) {
        float v  = sr[(j + 1024) & (WIN - 1)] * rs[j];
        long pos = base + j;
        if (pos >= 0 && pos < (long)out_size) atomicAdd(out + pos, v);
    }
}

extern "C" void kernel_launch(void* const* d_in, const int* in_sizes, int n_in,
                              void* d_out, int out_size, void* d_ws, size_t ws_size,
                              hipStream_t stream) {
    const float* mag = (const float*)d_in[0];
    const float* ph  = (const float*)d_in[1];
    float* out = (float*)d_out;
    float* rs  = (float*)d_ws;                   // 2048 floats = 8 KB scratch

    hipMemsetAsync(d_out, 0, (size_t)out_size * sizeof(float), stream);
    init_rs_kernel<<<(WIN + 255) / 256, 256, 0, stream>>>(rs);
    istft_kernel<<<NFRAMES, 256, 0, stream>>>(mag, ph, rs, out, out_size);
}